// Round 9
// baseline (385.634 us; speedup 1.0000x reference)
//
#include <hip/hip_runtime.h>
#include <hip/hip_bf16.h>

// SplineCNN block — HYBRID (r9 = r8 + agg uint restructure).
//   - conv1/conv2: S-scheme with hoisted dense basis + channel permutation
//     (r4 structure, unchanged from r8).
//   - conv3: Z-scheme (r0): Z = h3 @ Wp3 dense MFMA GEMM + gather-aggregate.
//     agg r9: lane = (channel-pair op, bin-group bg); uint Z loads (2 insts/
//     edge vs 4), pre-packed per-quarter shfl payloads (3 shfls/edge vs 4),
//     shl16/and bf16 converts. Same 512 B/edge traffic, ~25% fewer insts
//     (agg was 43% HBM + 44% VALUBusy = issue-co-bound).
// basis_fill emits BOTH edge formats:
//   g_ebas[slot] = dense 32-bin bf16 row (conv1/2), g_emeta[slot] = sparse
//   32-B record (agg).
// Degree sort: REMOVED (r6). Unconditional-4j: REMOVED (r7).
// Scan: two-level parallel (196-block partial + top + add).

#define EPS 1e-5f
#define MAXN 50176
#define MAXE 401408
#define SP2 904    // bf16 elems per S row (conv1/2): 864 spline + 32 root + 8 pad

typedef __attribute__((ext_vector_type(8))) short short8;
typedef __attribute__((ext_vector_type(4))) float floatx4;

__device__ int             g_deg[MAXN];
__device__ int             g_offs[MAXN + 1];
__device__ int             g_cursor[MAXN];
__device__ int             g_bsum[256];
__device__ int             g_esrc[MAXE];
__device__ __align__(16) uint4 g_ebas[MAXE * 4];   // dense interleaved rows
__device__ uint4           g_emeta[MAXE * 2];      // sparse 32-B records
__device__ __align__(16) __hip_bfloat16 g_h0[MAXN * 32];
__device__ __align__(16) __hip_bfloat16 g_h1[MAXN * 32];
__device__ __align__(16) __hip_bfloat16 g_h2[MAXN * 64];
__device__ __align__(16) __hip_bfloat16 g_h3[MAXN * 96];
__device__ __align__(16) __hip_bfloat16 g_Z[(size_t)MAXN * 896];
__device__ __align__(16) __hip_bfloat16 g_Wp1[28672];
__device__ __align__(16) __hip_bfloat16 g_Wp2[57344];
__device__ __align__(16) __hip_bfloat16 g_Wp3[86016];
__device__ float           g_stats[128];
__device__ int             g_isbf16;

__device__ __forceinline__ float loadf(const void* p, int i, bool bf)
{
    return bf ? (float)((const __hip_bfloat16*)p)[i] : ((const float*)p)[i];
}
__device__ __forceinline__ float bf16f(unsigned int u)
{
    return __uint_as_float(u << 16);
}
__device__ __forceinline__ unsigned short bfbits(float f)
{
    union { __hip_bfloat16 h; unsigned short u; } cv;
    cv.h = __float2bfloat16(f);
    return cv.u;
}
__device__ __forceinline__ void lds_fence()
{
    // ds_write -> cross-lane ds_read RAW hazard: lgkm only (not vmcnt).
    asm volatile("s_waitcnt lgkmcnt(0)" ::: "memory");
    __builtin_amdgcn_sched_barrier(0);
}

// ---------------- K1: zero-init scratch + wire dtype detect ----------------
__global__ void init_detect(const unsigned int* __restrict__ x, int n)
{
    int i = blockIdx.x * blockDim.x + threadIdx.x;
    if (blockIdx.x == 0 && threadIdx.x < 64) {
        int lane = threadIdx.x;
        int cnt = 0;
        for (int k = lane; k < 256; k += 64) {
            unsigned int lo = x[k] & 0xFFFFu;
            int ex = (int)((lo >> 7) & 0xFFu);
            if (lo == 0u || (ex >= 96 && ex <= 140)) cnt++;
        }
#pragma unroll
        for (int o = 1; o < 64; o <<= 1) cnt += __shfl_xor(cnt, o, 64);
        if (lane == 0) g_isbf16 = (cnt >= 200) ? 1 : 0;
    }
    if (i < n) { g_deg[i] = 0; g_cursor[i] = 0; }
    if (i < 128) g_stats[i] = 0.0f;
}

// ---------------- weight pack helpers (device) ----------------
// conv1/2 K axis = positions; position p within a 32-wide bin row holds
// channel 2*(p&15) + (p>>4)  (the conv1/2 A-load permutation).
template <int COUT>
__device__ __forceinline__ void prep_ws_dev(const void* W, const void* root,
                                            __hip_bfloat16* Wp, int t, bool bf)
{
    int j = t & 7;
    int lane = (t >> 3) & 63;
    int rest = t >> 9;
    int kk = rest % 28;
    int nt = rest / 28;
    int k = kk * 32 + (lane >> 4) * 8 + j;   // physical K position
    int o = nt * 16 + (lane & 15);
    float v;
    if (k < 864) {
        int bin = k >> 5, p = k & 31;
        int ch = 2 * (p & 15) + (p >> 4);
        v = loadf(W, (bin * 32 + ch) * COUT + o, bf);
    } else {
        int p = k - 864;
        int ch = 2 * (p & 15) + (p >> 4);
        v = loadf(root, ch * COUT + o, bf);
    }
    Wp[t] = __float2bfloat16(v);
}

// conv3 Z-gemm pack (r0 layout): KPAD=96, NTOT=896 = 28 groups x 32 cols;
// column group kw<27 = spline weight W3[kw], kw=27 = root. Rows 67..95 zero.
__device__ __forceinline__ void prep_w3_dev(const void* W, const void* root,
                                            __hip_bfloat16* Wp, int t, bool bf)
{
    const int KB = 3;   // KPAD=96 -> 3 K-tiles
    int j = t & 7;
    int lane = (t >> 3) & 63;
    int rest = t >> 9;
    int kk = rest % KB;
    int nt = rest / KB;
    int k = kk * 32 + (lane >> 4) * 8 + j;
    int ncol = nt * 16 + (lane & 15);
    int kw = ncol >> 5;
    int o = ncol & 31;
    float v = 0.0f;
    if (k < 67)
        v = (kw < 27) ? loadf(W, (kw * 67 + k) * 32 + o, bf)
                      : loadf(root, k * 32 + o, bf);
    Wp[t] = __float2bfloat16(v);
}

// ---------------- K2: degree count + cast x + pack all weights ----------------
__global__ void misc_kernel(const int* __restrict__ dst, const void* __restrict__ x,
                            const void* W1, const void* r1,
                            const void* W2, const void* r2,
                            const void* W3, const void* r3, int E, int N)
{
    int t = blockIdx.x * blockDim.x + threadIdx.x;
    const bool bf = (g_isbf16 != 0);
    if (t < E) { atomicAdd(&g_deg[dst[t]], 1); return; }
    t -= E;
    int nx = N * 32;
    if (t < nx) { g_h0[t] = __float2bfloat16(loadf(x, t, bf)); return; }
    t -= nx;
    if (t < 28672) { prep_ws_dev<32>(W1, r1, g_Wp1, t, bf); return; }
    t -= 28672;
    if (t < 57344) { prep_ws_dev<64>(W2, r2, g_Wp2, t, bf); return; }
    t -= 57344;
    if (t < 86016) { prep_w3_dev(W3, r3, g_Wp3, t, bf); return; }
}

// ---------------- K3a: per-block scan (256 elems/block) ----------------
__global__ void scan_blk(int n)
{
    __shared__ int buf[256];
    int tid = threadIdx.x;
    int i = blockIdx.x * 256 + tid;
    int v = (i < n) ? g_deg[i] : 0;
    buf[tid] = v;
    __syncthreads();
    for (int o = 1; o < 256; o <<= 1) {
        int t = (tid >= o) ? buf[tid - o] : 0;
        __syncthreads();
        buf[tid] += t;
        __syncthreads();
    }
    if (i < n) g_offs[i] = buf[tid] - v;   // block-local exclusive
    if (tid == 255) g_bsum[blockIdx.x] = buf[255];
}

// ---------------- K3b: scan of block sums (1 block; nb <= 256) ----------------
__global__ void scan_top(int nb, int n)
{
    __shared__ int buf[256];
    int tid = threadIdx.x;
    int v = (tid < nb) ? g_bsum[tid] : 0;
    buf[tid] = v;
    __syncthreads();
    for (int o = 1; o < 256; o <<= 1) {
        int t = (tid >= o) ? buf[tid - o] : 0;
        __syncthreads();
        buf[tid] += t;
        __syncthreads();
    }
    if (tid < nb) g_bsum[tid] = buf[tid] - v;   // exclusive
    if (tid == nb - 1) g_offs[n] = buf[tid];    // total = E
}

// ---------------- K3c: add block offsets ----------------
__global__ void scan_add(int n)
{
    int i = blockIdx.x * 256 + threadIdx.x;
    if (i < n) g_offs[i] += g_bsum[i >> 8];
}

// ---------------- K4: basis + CSR fill (dense rows + sparse records) -------
__global__ void basis_fill(const void* __restrict__ attr,
                           const int* __restrict__ src,
                           const int* __restrict__ dst, int E)
{
    int e = blockIdx.x * blockDim.x + threadIdx.x;
    if (e >= E) return;
    const bool bf = (g_isbf16 != 0);
    float f[3];
    int lo[3];
#pragma unroll
    for (int d = 0; d < 3; ++d) {
        float a = loadf(attr, e * 3 + d, bf);
        float s = a * 3.0f;
        float l = floorf(s);
        lo[d] = (int)l;
        f[d] = s - l;
    }
    const int p3[3] = {1, 3, 9};
    int wx8[8];
    unsigned short bb[8];
    unsigned int wxp0 = 0, wxp1 = 0;
#pragma unroll
    for (int b = 0; b < 8; ++b) {
        float w = 1.0f;
        int id = 0;
#pragma unroll
        for (int d = 0; d < 3; ++d) {
            int bit = (b >> d) & 1;
            w *= bit ? f[d] : (1.0f - f[d]);
            id += ((lo[d] + bit) % 3) * p3[d];
        }
        wx8[b] = id;
        bb[b] = bfbits(w);
        if (b < 4) wxp0 |= (unsigned int)id << (8 * b);
        else       wxp1 |= (unsigned int)id << (8 * (b - 4));
    }
    // densify, pair-interleaved: u32 word i = (bin i | bin i+16 << 16)
    unsigned wds[16];
#pragma unroll
    for (int i = 0; i < 16; ++i) {
        unsigned w = 0;
#pragma unroll
        for (int b = 0; b < 8; ++b) {
            if (wx8[b] == i)      w |= (unsigned)bb[b];
            if (wx8[b] == i + 16) w |= (unsigned)bb[b] << 16;
        }
        wds[i] = w;
    }
    int d = dst[e];
    int p = atomicAdd(&g_cursor[d], 1);
    int slot = g_offs[d] + p;
    int sv = src[e];
    uint4* out4 = &g_ebas[(size_t)slot * 4];
    out4[0] = make_uint4(wds[0],  wds[1],  wds[2],  wds[3]);
    out4[1] = make_uint4(wds[4],  wds[5],  wds[6],  wds[7]);
    out4[2] = make_uint4(wds[8],  wds[9],  wds[10], wds[11]);
    out4[3] = make_uint4(wds[12], wds[13], wds[14], wds[15]);
    g_esrc[slot] = sv;
    // sparse record for agg_kernel
    g_emeta[slot * 2] = make_uint4(wxp0, wxp1,
                                   (unsigned int)bb[0] | ((unsigned int)bb[1] << 16),
                                   (unsigned int)bb[2] | ((unsigned int)bb[3] << 16));
    g_emeta[slot * 2 + 1] = make_uint4(
        (unsigned int)bb[4] | ((unsigned int)bb[5] << 16),
        (unsigned int)bb[6] | ((unsigned int)bb[7] << 16),
        (unsigned int)sv, 0u);
}

// ---------------- fused conv (CIN=32), 8 nodes / 512 thr (r4) ----------------
// IN_SEL: 0 = g_h0, 1 = g_h1.  OUT_SEL: 1 = g_h1 (+ELU), 2 = g_h2 (raw).
template <int COUT, bool ELU, int IN_SEL, int OUT_SEL>
__global__ __launch_bounds__(512, 8) void fused_conv(const void* __restrict__ bias,
                                                     int N)
{
    __shared__ unsigned short Sb[8 * SP2];
    __shared__ __align__(16) unsigned basb[8][16][16];
    __shared__ int ssrc[8][16];
    __shared__ float invd[8];
    int tid = threadIdx.x, wid = tid >> 6, lane = tid & 63;
    int nbase = blockIdx.x * 8;
    const bool bf = (g_isbf16 != 0);
    const unsigned short* xptr = (IN_SEL == 0) ? (const unsigned short*)g_h0
                                               : (const unsigned short*)g_h1;
    const __hip_bfloat16* Wp = (COUT == 32) ? g_Wp1 : g_Wp2;

    int n = nbase + wid;
    int m = lane & 15, quad = lane >> 4;

    // ---- phase 1: wave wid builds S row for its node via MFMA scatter-GEMM ----
    if (n < N) {
        int e0 = g_offs[n], e1 = g_offs[n + 1];
        floatx4 C00 = {}, C01 = {}, C10 = {}, C11 = {};
        for (int base = e0; base < e1; base += 16) {
            int cnt = e1 - base; if (cnt > 16) cnt = 16;
            {   // stage 16 interleaved basis rows (64 B each) + src ids
                int es = lane >> 2, part = lane & 3;
                uint4 v = make_uint4(0, 0, 0, 0);
                if (es < cnt) v = g_ebas[(size_t)(base + es) * 4 + part];
                *(uint4*)&basb[wid][es][part * 4] = v;
                if (lane < 16)
                    ssrc[wid][lane] = (lane < cnt) ? g_esrc[base + lane] : 0;
            }
            lds_fence();
            int jmax = (cnt + 3) >> 2;   // wave-uniform; zero rows beyond cnt
            unsigned a0w[4] = {0, 0, 0, 0}, a1w[4] = {0, 0, 0, 0};
            unsigned b0w[4] = {0, 0, 0, 0}, b1w[4] = {0, 0, 0, 0};
#pragma unroll
            for (int j = 0; j < 4; ++j) {
                if (j >= jmax) break;
                // K-permutation: fragment slot (quad, j) holds edge j*4+quad.
                int kidx = j * 4 + quad;
                int sn = ssrc[wid][kidx];
                unsigned pw = basb[wid][kidx][m];      // (bin m | bin m+16)
                // channels (2m, 2m+1) = tiles (0,1) row m, one dword
                unsigned hw = *((const unsigned*)xptr + (size_t)sn * 16 + m);
                unsigned sh = 16 * (j & 1);
                a0w[j >> 1] |= (hw & 0xFFFFu) << sh;
                a1w[j >> 1] |= (hw >> 16) << sh;
                b0w[j >> 1] |= (pw & 0xFFFFu) << sh;
                b1w[j >> 1] |= (pw >> 16) << sh;
            }
            union U { unsigned w[4]; short8 v; } A0, A1, B0, B1;
#pragma unroll
            for (int q = 0; q < 4; ++q) {
                A0.w[q] = a0w[q]; A1.w[q] = a1w[q];
                B0.w[q] = b0w[q]; B1.w[q] = b1w[q];
            }
            C00 = __builtin_amdgcn_mfma_f32_16x16x32_bf16(A0.v, B0.v, C00, 0, 0, 0);
            C01 = __builtin_amdgcn_mfma_f32_16x16x32_bf16(A0.v, B1.v, C01, 0, 0, 0);
            C10 = __builtin_amdgcn_mfma_f32_16x16x32_bf16(A1.v, B0.v, C10, 0, 0, 0);
            C11 = __builtin_amdgcn_mfma_f32_16x16x32_bf16(A1.v, B1.v, C11, 0, 0, 0);
        }
        // writeback (positions): C[mt][nt] lane: col=m (bin-in-tile),
        // rows quad*4+r -> S[bin*32 + mt*16 + quad*4 + r]
        unsigned short* Srow = Sb + wid * SP2;
        {
            floatx4 Cf[4] = {C00, C01, C10, C11};
#pragma unroll
            for (int f = 0; f < 4; ++f) {
                int mt = f >> 1, nt = f & 1;
                int bin = nt * 16 + m;
                if (bin < 27) {
                    union { unsigned short h[4]; uint2 u; } pk;
#pragma unroll
                    for (int r = 0; r < 4; ++r) pk.h[r] = bfbits(Cf[f][r]);
                    *(uint2*)(Srow + bin * 32 + mt * 16 + quad * 4) = pk.u;
                }
            }
        }
        if (lane < 32) {
            int ch = 2 * (lane & 15) + (lane >> 4);
            Srow[864 + lane] = xptr[(size_t)n * 32 + ch];
        }
        if (lane == 0) {
            int deg = e1 - e0;
            invd[wid] = 1.0f / (float)(deg < 1 ? 1 : deg);
        }
    }
    __syncthreads();

    // ---- phase 2: wave w = col-tile w of GEMM 16 x 896 @ 896 x COUT ----
    if (wid * 16 < COUT) {
        int mrow = m & 7;   // 8 nodes; rows 8..15 duplicate (discarded below)
        const unsigned short* Ab = Sb + mrow * SP2 + quad * 8;
        floatx4 accS = {}, accR = {};
#pragma unroll
        for (int kk = 0; kk < 28; ++kk) {
            short8 a = *(const short8*)(Ab + kk * 32);
            const short* bp = (const short*)Wp +
                ((size_t)(wid * 28 + kk) * 64 + lane) * 8;
            short8 b = *(const short8*)bp;
            if (kk < 27) accS = __builtin_amdgcn_mfma_f32_16x16x32_bf16(a, b, accS, 0, 0, 0);
            else         accR = __builtin_amdgcn_mfma_f32_16x16x32_bf16(a, b, accR, 0, 0, 0);
        }
        int o = wid * 16 + m;
        float bval = loadf(bias, o, bf);
#pragma unroll
        for (int r = 0; r < 4; ++r) {
            int slot = quad * 4 + r;
            if (slot >= 8) continue;
            int nn = nbase + slot;
            if (nn >= N) continue;
            float v = accS[r] * invd[slot] + accR[r] + bval;
            if (ELU) v = v > 0.0f ? v : expm1f(v);
            if (OUT_SEL == 1) g_h1[nn * 32 + o] = __float2bfloat16(v);
            else              g_h2[nn * 64 + o] = __float2bfloat16(v);
        }
    }
}

// ---------------- BN stats (reads g_h2) ----------------
__global__ void bn_reduce(int n)
{
    int tid = threadIdx.x;
    int c = tid & 63;
    int r = tid >> 6;
    float s = 0.0f, s2 = 0.0f;
    for (int i = blockIdx.x * 4 + r; i < n; i += gridDim.x * 4) {
        float v = (float)g_h2[i * 64 + c];
        s += v; s2 += v * v;
    }
    __shared__ float b1s[256], b2s[256];
    b1s[tid] = s; b2s[tid] = s2;
    __syncthreads();
    if (r == 0) {
        s  = b1s[c] + b1s[c + 64] + b1s[c + 128] + b1s[c + 192];
        s2 = b2s[c] + b2s[c + 64] + b2s[c + 128] + b2s[c + 192];
        atomicAdd(&g_stats[c], s);
        atomicAdd(&g_stats[64 + c], s2);
    }
}

// ---------------- h3 = [elu(bn(h2)), pos, 0-pad] (96 ch), coef inline -------
__global__ void h3_build(const void* __restrict__ pos,
                         const void* __restrict__ gamma,
                         const void* __restrict__ beta, int N)
{
    __shared__ float cf[128];
    int t = threadIdx.x;
    const bool bf = (g_isbf16 != 0);
    if (t < 64) {
        float inv_n = 1.0f / (float)N;
        float mu = g_stats[t] * inv_n;
        float var = g_stats[64 + t] * inv_n - mu * mu;
        float A = rsqrtf(var + EPS) * loadf(gamma, t, bf);
        cf[t] = A;
        cf[64 + t] = loadf(beta, t, bf) - mu * A;
    }
    __syncthreads();
    int idx = blockIdx.x * blockDim.x + t;
    if (idx >= N * 96) return;
    int n = idx / 96, ch = idx - n * 96;
    float v;
    if (ch < 64) {
        float h = (float)g_h2[n * 64 + ch];
        v = h * cf[ch] + cf[64 + ch];
        v = v > 0.0f ? v : expm1f(v);
    } else if (ch < 67) {
        v = loadf(pos, n * 3 + (ch - 64), bf);
    } else {
        v = 0.0f;
    }
    g_h3[(size_t)n * 96 + ch] = __float2bfloat16(v);
}

// ---------------- conv3 Z-path: dense GEMM Z = h3 @ Wp3 (r0) ----------------
// Wave swizzle: col-group-major so the NTW waves sharing an h3 row are
// dispatch-adjacent (L2-hot) -> h3 fetched ~once instead of NTW times.
template <int STRIDE, int NTOT, int KPAD, int NPW>
__global__ __launch_bounds__(256) void gemm_kernel(int MT, int NTW)
{
    int gid = blockIdx.x * 256 + threadIdx.x;
    int gw = gid >> 6, lane = gid & 63;
    if (gw >= MT * NTW) return;
    int mt = gw / NTW;                 // consecutive waves share mt
    int ntb = (gw % NTW) * NPW;
    int m = lane & 15, quad = lane >> 4;
    const short* hrow = (const short*)g_h3 + (size_t)(mt * 16 + m) * STRIDE;
    floatx4 acc[NPW] = {};
    const int KB = KPAD / 32;
#pragma unroll
    for (int kk = 0; kk < KB; ++kk) {
        short8 a = *(const short8*)(hrow + kk * 32 + quad * 8);
#pragma unroll
        for (int i = 0; i < NPW; ++i) {
            const short* bp = (const short*)g_Wp3 +
                (((size_t)(ntb + i) * KB + kk) * 64 + lane) * 8;
            short8 b = *(const short8*)bp;
            acc[i] = __builtin_amdgcn_mfma_f32_16x16x32_bf16(a, b, acc[i], 0, 0, 0);
        }
    }
    int col = lane & 15;
    int rowbase = mt * 16 + quad * 4;
#pragma unroll
    for (int i = 0; i < NPW; ++i) {
        int ncol = (ntb + i) * 16 + col;
#pragma unroll
        for (int r = 0; r < 4; ++r)
            g_Z[(size_t)(rowbase + r) * NTOT + ncol] = __float2bfloat16(acc[i][r]);
    }
}

// ---------------- conv3: gather-aggregate, uint loads (r9) ----------------
// lane = (op = lane&15: channel pair 2op,2op+1; bg = lane>>4: bins bg, bg+4).
// Per 16-edge chunk each quarter-wave holds all records pre-packed for its
// bin pair -> per edge: 3 shfls + 2 uint loads + 4 fmacs. Bin-group totals
// reduced via shfl_xor(16/32); lanes 0..15 write packed channel pairs.
template <int COUT, int NTOT>
__global__ __launch_bounds__(256) void agg_kernel(const void* __restrict__ bias,
                                                  void* __restrict__ out_ext, int N)
{
    int wid = threadIdx.x >> 6, lane = threadIdx.x & 63;
    int n = blockIdx.x * 4 + wid;
    if (n >= N) return;
    const bool bf = (g_isbf16 != 0);
    const unsigned short* zp = (const unsigned short*)g_Z;
    int e0 = g_offs[n], e1 = g_offs[n + 1];
    int op = lane & 15, bg = lane >> 4;
    float acc0 = 0.0f, acc1 = 0.0f;
    for (int base = e0; base < e1; base += 16) {
        int cnt = e1 - base; if (cnt > 16) cnt = 16;
        uint4 r0 = make_uint4(0, 0, 0, 0), r1 = make_uint4(0, 0, 0, 0);
        if (op < cnt) {   // each quarter holds copies of the 16 records
            size_t le = (size_t)(base + op) * 2;
            r0 = g_emeta[le];
            r1 = g_emeta[le + 1];
        }
        // pre-pack for this quarter's bins (bg, bg+4):
        // r0 = wx03,wx47,bas01,bas23 ; r1 = bas45,bas67,src,0
        unsigned wxpk = ((r0.x >> (8 * bg)) & 0xFFu)
                      | (((r0.y >> (8 * bg)) & 0xFFu) << 8);
        unsigned blo = (bg & 2) ? r0.w : r0.z;   // bas[bg]   word
        unsigned bhi = (bg & 2) ? r1.y : r1.x;   // bas[bg+4] word
        unsigned baspk = (bg & 1) ? ((blo >> 16) | (bhi & 0xFFFF0000u))
                                  : ((blo & 0xFFFFu) | (bhi << 16));
        int srcv = (int)r1.z;
#pragma unroll 2
        for (int j = 0; j < cnt; ++j) {
            int sl = (bg << 4) + j;
            int sn = __shfl(srcv, sl, 64);
            unsigned wx2 = (unsigned)__shfl((int)wxpk, sl, 64);
            unsigned bs2 = (unsigned)__shfl((int)baspk, sl, 64);
            const unsigned short* zr = zp + (size_t)sn * NTOT;
            unsigned z0 = *(const unsigned*)(zr + ((wx2 & 0xFFu) << 5) + 2 * op);
            unsigned z1 = *(const unsigned*)(zr + (((wx2 >> 8) & 0xFFu) << 5) + 2 * op);
            float b0 = __uint_as_float(bs2 << 16);
            float b1 = __uint_as_float(bs2 & 0xFFFF0000u);
            acc0 += b0 * __uint_as_float(z0 << 16)
                  + b1 * __uint_as_float(z1 << 16);
            acc1 += b0 * __uint_as_float(z0 & 0xFFFF0000u)
                  + b1 * __uint_as_float(z1 & 0xFFFF0000u);
        }
    }
    acc0 += __shfl_xor(acc0, 16, 64);
    acc0 += __shfl_xor(acc0, 32, 64);
    acc1 += __shfl_xor(acc1, 16, 64);
    acc1 += __shfl_xor(acc1, 32, 64);
    if (lane >= 16) return;
    int deg = e1 - e0;
    float inv = 1.0f / (float)(deg < 1 ? 1 : deg);
    unsigned zroot = *(const unsigned*)(zp + (size_t)n * NTOT + 27 * COUT + 2 * op);
    float v0 = acc0 * inv + __uint_as_float(zroot << 16)
             + loadf(bias, 2 * op, bf);
    float v1 = acc1 * inv + __uint_as_float(zroot & 0xFFFF0000u)
             + loadf(bias, 2 * op + 1, bf);
    if (bf) {
        unsigned pk = (unsigned)bfbits(v0) | ((unsigned)bfbits(v1) << 16);
        *(unsigned*)((unsigned short*)out_ext + (size_t)n * COUT + 2 * op) = pk;
    } else {
        float* po = (float*)out_ext + (size_t)n * COUT + 2 * op;
        po[0] = v0;
        po[1] = v1;
    }
}

extern "C" void kernel_launch(void* const* d_in, const int* in_sizes, int n_in,
                              void* d_out, int out_size, void* d_ws, size_t ws_size,
                              hipStream_t stream)
{
    const void* x      = d_in[0];
    const int*  eindex = (const int*)d_in[1];
    const void* eattr  = d_in[2];
    const void* pos    = d_in[3];
    const void* W1     = d_in[4];
    const void* root1  = d_in[5];
    const void* b1     = d_in[6];
    const void* W2     = d_in[7];
    const void* root2  = d_in[8];
    const void* b2     = d_in[9];
    const void* gamma  = d_in[10];
    const void* beta   = d_in[11];
    const void* W3     = d_in[12];
    const void* root3  = d_in[13];
    const void* b3     = d_in[14];
    (void)d_ws; (void)ws_size; (void)n_in; (void)out_size;

    const int N = in_sizes[0] / 32;
    const int E = in_sizes[1] / 2;
    const int* srcp = eindex;
    const int* dstp = eindex + E;

    init_detect<<<(N + 255) / 256, 256, 0, stream>>>((const unsigned int*)x, N);
    {
        int tot = E + N * 32 + 28672 + 57344 + 86016;
        misc_kernel<<<(tot + 255) / 256, 256, 0, stream>>>(
            dstp, x, W1, root1, W2, root2, W3, root3, E, N);
    }
    // two-level parallel scan
    int nb = (N + 255) / 256;   // 196 <= 256
    scan_blk<<<nb, 256, 0, stream>>>(N);
    scan_top<<<1, 256, 0, stream>>>(nb, N);
    scan_add<<<nb, 256, 0, stream>>>(N);
    basis_fill<<<(E + 255) / 256, 256, 0, stream>>>(eattr, srcp, dstp, E);

    int nb8 = (N + 7) / 8;
    fused_conv<32, true, 0, 1><<<nb8, 512, 0, stream>>>(b1, N);
    fused_conv<64, false, 1, 2><<<nb8, 512, 0, stream>>>(b2, N);
    bn_reduce<<<120, 256, 0, stream>>>(N);
    h3_build<<<(N * 96 + 255) / 256, 256, 0, stream>>>(pos, gamma, beta, N);
    {
        const int NTOT = 28 * 32, KPAD = 96, NPW = 4;
        int NTW = (NTOT / 16) / NPW;   // 14
        int MT = (N + 15) / 16;
        int waves = MT * NTW;
        gemm_kernel<96, NTOT, KPAD, NPW><<<(waves + 3) / 4, 256, 0, stream>>>(MT, NTW);
    }
    agg_kernel<32, 28 * 32><<<(N + 3) / 4, 256, 0, stream>>>(b3, d_out, N);
}